// Round 1
// 157.065 us; speedup vs baseline: 1.0775x; 1.0775x over previous
//
#include <hip/hip_runtime.h>

#define Bn 4
#define Qn 128
#define Kn 1024
#define Dn 512   // DQ = DK = DV = 512
#define Hn 256

// tanh(x) = 1 - 2/(1 + e^{2x}).  Inf-safe: e->inf => rcp(inf)=0 => 1.
__device__ __forceinline__ float fast_tanh(float x) {
    float e = __expf(2.0f * x);
    return 1.0f - 2.0f * __builtin_amdgcn_rcpf(1.0f + e);
}

// ---------------------------------------------------------------------------
// Kernel 1: projections GEMM [4608x512]@[512x256], 64x64 tile, BK=64.
// v2: 512 threads/block (8 waves). Waves 0-3 compute kk 0..31 of each staged
// k-tile, waves 4-7 compute kk 32..63 (intra-block split-K), partials merged
// through LDS at the end. This doubles waves/SIMD (1 -> 2.25 avg, 4 on
// doubled CUs since 2 blocks/CU fit) and halves the prefetch register
// footprint (32 -> 16 VGPRs), giving the scheduler headroom to pipeline
// ds_read_b128 across kk iterations instead of eating ~120 cyc LDS latency
// serially every kk (the v1 failure mode: 68 VGPRs, VALUBusy 0.7%).
// ---------------------------------------------------------------------------
#define PBK 64

__global__ __launch_bounds__(512, 4) void proj_kernel(
    const float* __restrict__ queries, const float* __restrict__ keys,
    const float* __restrict__ Wq, const float* __restrict__ Wk,
    const int* __restrict__ valid_lens,
    float* __restrict__ qproj, float* __restrict__ kproj)
{
    const int blk = blockIdx.x;         // mt(72) * 4 + nt
    const int nt = blk & 3;
    const int mt = blk >> 2;
    const int t = threadIdx.x;
    const float* Asrc; const float* W; float* Dst;
    int m0;
    if (mt < 8) {
        m0 = mt * 64;
        Asrc = queries; W = Wq; Dst = qproj;
    } else {
        int r0 = (mt - 8) * 64;
        int b = r0 >> 10;
        if ((r0 & 1023) >= valid_lens[b]) return;   // tile fully masked
        m0 = r0;
        Asrc = keys; W = Wk; Dst = kproj;
    }
    const int n0 = nt * 64;

    __shared__ float s_a[PBK][68];      // A^T tile [k][m], pad 68 (17408 B)
    __shared__ float s_b[PBK][64];      // B tile   [k][n]   (16384 B)

    const int tt   = t & 255;           // position within half
    const int kh   = t >> 8;            // k-half: 0 -> kk 0..31, 1 -> kk 32..63
    const int trow = tt >> 4;           // 0..15 (x4 m)
    const int tcol = tt & 15;           // 0..15 (x4 n)
    const int kklo = kh << 5;

    // staging layout: idx = t + i*512 -> row = (t>>4) + i*32, c4 = t&15
    const int lrow = t >> 4;            // 0..31
    const int lc4  = t & 15;

    float acc[4][4] = {{0.f}};
    float4 ra[2], rb[2];

    #pragma unroll
    for (int i = 0; i < 2; ++i) {       // preload kt=0
        ra[i] = *(const float4*)(Asrc + (size_t)(m0 + lrow + i * 32) * Dn + lc4 * 4);
        rb[i] = *(const float4*)(W + (size_t)(lrow + i * 32) * Hn + n0 + lc4 * 4);
    }

    for (int kt = 0; kt < 8; ++kt) {
        __syncthreads();                // prev compute done before overwrite
        #pragma unroll
        for (int i = 0; i < 2; ++i) {   // regs -> LDS (waits vmcnt here)
            int row = lrow + i * 32;
            s_a[lc4 * 4 + 0][row] = ra[i].x;
            s_a[lc4 * 4 + 1][row] = ra[i].y;
            s_a[lc4 * 4 + 2][row] = ra[i].z;
            s_a[lc4 * 4 + 3][row] = ra[i].w;
            *(float4*)&s_b[row][lc4 * 4] = rb[i];
        }
        __syncthreads();
        if (kt < 7) {                   // prefetch kt+1 (overlaps compute)
            const int d0n = (kt + 1) * PBK;
            #pragma unroll
            for (int i = 0; i < 2; ++i) {
                ra[i] = *(const float4*)(Asrc + (size_t)(m0 + lrow + i * 32) * Dn + d0n + lc4 * 4);
                rb[i] = *(const float4*)(W + (size_t)(d0n + lrow + i * 32) * Hn + n0 + lc4 * 4);
            }
        }
        #pragma unroll
        for (int kk = 0; kk < 32; ++kk) {
            float4 a4 = *(const float4*)&s_a[kklo + kk][trow * 4];
            float4 b4 = *(const float4*)&s_b[kklo + kk][tcol * 4];
            float a[4] = {a4.x, a4.y, a4.z, a4.w};
            float b[4] = {b4.x, b4.y, b4.z, b4.w};
            #pragma unroll
            for (int i = 0; i < 4; ++i)
                #pragma unroll
                for (int j = 0; j < 4; ++j)
                    acc[i][j] += a[i] * b[j];
        }
    }

    // merge the two k-halves through LDS (s_a region: 4352 floats = 256*17,
    // stride 17 keeps the scalar accesses conflict-free)
    __syncthreads();
    float* red = &s_a[0][0];
    if (kh) {
        #pragma unroll
        for (int i = 0; i < 4; ++i)
            #pragma unroll
            for (int j = 0; j < 4; ++j)
                red[tt * 17 + i * 4 + j] = acc[i][j];
    }
    __syncthreads();
    if (!kh) {
        #pragma unroll
        for (int i = 0; i < 4; ++i) {
            float4 o;
            o.x = acc[i][0] + red[tt * 17 + i * 4 + 0];
            o.y = acc[i][1] + red[tt * 17 + i * 4 + 1];
            o.z = acc[i][2] + red[tt * 17 + i * 4 + 2];
            o.w = acc[i][3] + red[tt * 17 + i * 4 + 3];
            *(float4*)(Dst + (size_t)(m0 + trow * 4 + i) * Hn + n0 + tcol * 4) = o;
        }
    }
}

// ---------------------------------------------------------------------------
// Kernel 2: e = exp(score) (max-free: |score| <= sum|wv|) + atomic rowsum.
// k-tile = 16 (LDS 21.8 KB -> 7 blocks/CU), lane = kloc(16) x h-quarter(4),
// each lane sums 64 h; two shfl_xor combine. Grid 8192, ~11 active blocks/CU.
// ---------------------------------------------------------------------------
#define SK_KT 16
#define SK_PAD 260

__global__ __launch_bounds__(256) void score_kernel(
    const float* __restrict__ qproj, const float* __restrict__ kproj,
    const float* __restrict__ wv, const int* __restrict__ valid_lens,
    float* __restrict__ escores, float* __restrict__ rowsum)
{
    const int blk = blockIdx.x;             // ((b*32 + qt)*64 + kt)
    const int kt = blk & 63;
    const int qt = (blk >> 6) & 31;
    const int b  = blk >> 11;
    const int vlen = valid_lens[b];
    const int k0 = kt * SK_KT;
    if (k0 >= vlen) return;                 // fully-masked tile
    const int q0 = qt * 4;
    const int t = threadIdx.x;

    __shared__ float s_k[SK_KT * SK_PAD];   // 16640 B
    __shared__ float s_q[4 * Hn];           // 4 KB
    __shared__ float s_wv[Hn];              // 1 KB

    {
        const float4* src = reinterpret_cast<const float4*>(
            kproj + ((size_t)b * Kn + k0) * Hn);
        #pragma unroll
        for (int i = 0; i < 4; ++i) {       // 16 rows x 64 float4
            int idx = t + i * 256;
            int row = idx >> 6, c4 = idx & 63;
            *reinterpret_cast<float4*>(&s_k[row * SK_PAD + c4 * 4]) = src[idx];
        }
        reinterpret_cast<float4*>(s_q)[t] = reinterpret_cast<const float4*>(
            qproj + ((size_t)b * Qn + q0) * Hn)[t];
        if (t < 64)
            reinterpret_cast<float4*>(s_wv)[t] =
                reinterpret_cast<const float4*>(wv)[t];
    }
    __syncthreads();

    const int wave = t >> 6;
    const int lane = t & 63;
    const int kloc = lane & 15;
    const int hq   = lane >> 4;             // h-quarter: 64 h each

    const float4* kr = reinterpret_cast<const float4*>(&s_k[kloc * SK_PAD + hq * 64]);
    const float4* qr = reinterpret_cast<const float4*>(&s_q[wave * Hn + hq * 64]);
    const float4* wr = reinterpret_cast<const float4*>(&s_wv[hq * 64]);

    float s = 0.0f;
    #pragma unroll
    for (int i = 0; i < 16; ++i) {          // 16 float4 = 64 h per lane
        float4 kv = kr[i];
        float4 qv = qr[i];
        float4 wq = wr[i];
        s += wq.x * fast_tanh(qv.x + kv.x);
        s += wq.y * fast_tanh(qv.y + kv.y);
        s += wq.z * fast_tanh(qv.z + kv.z);
        s += wq.w * fast_tanh(qv.w + kv.w);
    }
    s += __shfl_xor(s, 16, 64);
    s += __shfl_xor(s, 32, 64);

    const int k = k0 + kloc;
    float e = 0.0f;
    if (lane < 16 && k < vlen) {
        e = __expf(s);
        escores[((size_t)b * Qn + q0 + wave) * Kn + k] = e;
    }
    #pragma unroll
    for (int off = 32; off; off >>= 1)
        e += __shfl_xor(e, off, 64);
    if (lane == 0)
        atomicAdd(&rowsum[b * Qn + q0 + wave], e);
}

// ---------------------------------------------------------------------------
// Kernel 3a: uniform split-k AV partials. escores fully zeroed -> masked k
// contribute 0 -> NO vlen dependence, free grid shaping, zero imbalance.
// Block = (b, 8q, 256d-half, 256k-chunk) = 512 blocks. 8 loads in flight.
// Partials land in ws (reuses the dead kproj region).
// ---------------------------------------------------------------------------
__global__ __launch_bounds__(256) void av_part_kernel(
    const float* __restrict__ escores, const float* __restrict__ values,
    float* __restrict__ parts)
{
    const int blk = blockIdx.x;         // (((b*16+qt)*2+dh)*4+kc)
    const int kc = blk & 3;
    const int dh = (blk >> 2) & 1;
    const int qt = (blk >> 3) & 15;
    const int b  = blk >> 7;
    const int t = threadIdx.x;
    const int q0 = qt * 8;
    const int kb = kc * 256;
    const int d  = dh * 256 + t;

    __shared__ float s_e[8][256];       // 8 KB
    #pragma unroll
    for (int i = 0; i < 2; ++i) {
        int idx = t + i * 256;
        int row = idx >> 6, c4 = idx & 63;
        *(float4*)&s_e[row][c4 * 4] = *(const float4*)(
            escores + ((size_t)(b * Qn + q0 + row)) * Kn + kb + c4 * 4);
    }
    __syncthreads();

    const float* vb = values + ((size_t)b * Kn + kb) * Dn + d;
    float acc[8] = {0.f};
    #pragma unroll 2
    for (int k = 0; k < 256; k += 4) {
        float v0 = vb[(size_t)(k + 0) * Dn];
        float v1 = vb[(size_t)(k + 1) * Dn];
        float v2 = vb[(size_t)(k + 2) * Dn];
        float v3 = vb[(size_t)(k + 3) * Dn];
        #pragma unroll
        for (int j = 0; j < 8; ++j) {
            float4 e4 = *(const float4*)&s_e[j][k];  // wave-uniform broadcast
            acc[j] += e4.x * v0 + e4.y * v1 + e4.z * v2 + e4.w * v3;
        }
    }
    float* pp = parts + (size_t)kc * (Bn * Qn * Dn)
                      + ((size_t)(b * Qn + q0)) * Dn + d;
    #pragma unroll
    for (int j = 0; j < 8; ++j)
        pp[(size_t)j * Dn] = acc[j];
}

// ---------------------------------------------------------------------------
// Kernel 3b: out = (sum of 4 partials) * rcp(rowsum[row]).
// ---------------------------------------------------------------------------
__global__ __launch_bounds__(256) void reduce_kernel(
    const float* __restrict__ parts, const float* __restrict__ rowsum,
    float* __restrict__ out)
{
    const int idx = blockIdx.x * 256 + threadIdx.x;   // float4 index, 65536 total
    const int row = (idx * 4) >> 9;                   // / Dn
    const float inv = __builtin_amdgcn_rcpf(rowsum[row]);
    const float4* p = (const float4*)parts;
    float4 a = p[idx];
    float4 b = p[idx + 65536];
    float4 c = p[idx + 131072];
    float4 d = p[idx + 196608];
    float4 o;
    o.x = (a.x + b.x + c.x + d.x) * inv;
    o.y = (a.y + b.y + c.y + d.y) * inv;
    o.z = (a.z + b.z + c.z + d.z) * inv;
    o.w = (a.w + b.w + c.w + d.w) * inv;
    ((float4*)out)[idx] = o;
}

// ---------------------------------------------------------------------------
extern "C" void kernel_launch(void* const* d_in, const int* in_sizes, int n_in,
                              void* d_out, int out_size, void* d_ws, size_t ws_size,
                              hipStream_t stream) {
    const float* queries    = (const float*)d_in[0];
    const float* keys       = (const float*)d_in[1];
    const float* values     = (const float*)d_in[2];
    const int*   valid_lens = (const int*)  d_in[3];
    const float* Wq         = (const float*)d_in[4];
    const float* Wk         = (const float*)d_in[5];
    const float* wv         = (const float*)d_in[6];
    float* out = (float*)d_out;

    float* qproj   = (float*)d_ws;                // [B*Q, H]     131072 f
    float* kproj   = qproj + Bn * Qn * Hn;        // [B*K, H]    1048576 f
    float* escores = kproj + Bn * Kn * Hn;        // [B*Q, K]     524288 f
    float* rowsum  = escores + Bn * Qn * Kn;      // [B*Q]           512 f
    float* parts   = kproj;                       // alias: kproj dead after score
                                                  // 4*[B*Q,D] = 1048576 f (fits)

    // zero escores (masked k stay 0) + rowsum in one memset
    hipMemsetAsync(escores, 0, (size_t)(Bn * Qn * Kn + Bn * Qn) * sizeof(float),
                   stream);
    proj_kernel<<<288, 512, 0, stream>>>(queries, keys, Wq, Wk, valid_lens,
                                         qproj, kproj);
    score_kernel<<<Bn * 32 * 64, 256, 0, stream>>>(qproj, kproj, wv,
                                                   valid_lens, escores, rowsum);
    av_part_kernel<<<512, 256, 0, stream>>>(escores, values, parts);
    reduce_kernel<<<256, 256, 0, stream>>>(parts, rowsum, out);
}

// Round 2
// 153.398 us; speedup vs baseline: 1.1032x; 1.0239x over previous
//
#include <hip/hip_runtime.h>

#define Bn 4
#define Qn 128
#define Kn 1024
#define Dn 512   // DQ = DK = DV = 512
#define Hn 256

// tanh(x) = 1 - 2/(1 + e^{2x}).  Inf-safe: e->inf => rcp(inf)=0 => 1.
__device__ __forceinline__ float fast_tanh(float x) {
    float e = __expf(2.0f * x);
    return 1.0f - 2.0f * __builtin_amdgcn_rcpf(1.0f + e);
}

// ---------------------------------------------------------------------------
// Kernel 1: projections GEMM [4608x512]@[512x256], 64x64 tile.
// v3: block-level split-K (kc in {0,1}, each 256 deep) ON TOP OF the v2
// intra-block split (8 waves: waves 0-3 do kk 0..31, waves 4-7 do kk 32..63).
//  - grid 288 -> 576 (active ~320 after masking): ~2x CU coverage, the v2
//    failure mode was 0.6 active blocks/CU with most CUs idle.
//  - serial staged K-rounds per block: 8 -> 4 (halves latency-critical depth;
//    cold-L2 runs pay HBM latency per round).
//  - No atomics: kc=0/1 write disjoint partial buffers proj0/proj1; the score
//    kernel sums them while staging (cheap L2 reads).
// ---------------------------------------------------------------------------
#define PBK 64

__global__ __launch_bounds__(512, 4) void proj_kernel(
    const float* __restrict__ queries, const float* __restrict__ keys,
    const float* __restrict__ Wq, const float* __restrict__ Wk,
    const int* __restrict__ valid_lens,
    float* __restrict__ proj0, float* __restrict__ proj1)
{
    const int blk = blockIdx.x;         // ((mt*4)+nt)*2 + kc
    const int kc = blk & 1;
    const int nt = (blk >> 1) & 3;
    const int mt = blk >> 3;            // 0..71
    const int t = threadIdx.x;
    const float* Asrc; const float* W;
    int m0, drow;
    if (mt < 8) {                       // query rows (512 = B*Q)
        m0 = mt * 64;
        drow = m0;
        Asrc = queries; W = Wq;
    } else {                            // key rows (4096 = B*K)
        int r0 = (mt - 8) * 64;
        int b = r0 >> 10;
        if ((r0 & 1023) >= valid_lens[b]) return;   // tile fully masked
        m0 = r0;
        drow = 512 + r0;
        Asrc = keys; W = Wk;
    }
    const int n0 = nt * 64;
    const int k0 = kc * 256;            // this block's K-chunk
    float* Dst = (kc ? proj1 : proj0) + (size_t)drow * Hn;

    __shared__ float s_a[PBK][68];      // A^T tile [k][m], pad 68 (17408 B)
    __shared__ float s_b[PBK][64];      // B tile   [k][n]   (16384 B)

    const int tt   = t & 255;           // position within k-half
    const int kh   = t >> 8;            // 0 -> kk 0..31, 1 -> kk 32..63
    const int trow = tt >> 4;           // 0..15 (x4 m)
    const int tcol = tt & 15;           // 0..15 (x4 n)
    const int kklo = kh << 5;

    const int lrow = t >> 4;            // 0..31 (staging row)
    const int lc4  = t & 15;

    float acc[4][4] = {{0.f}};
    float4 ra[2], rb[2];

    #pragma unroll
    for (int i = 0; i < 2; ++i) {       // preload kt=0
        ra[i] = *(const float4*)(Asrc + (size_t)(m0 + lrow + i * 32) * Dn + k0 + lc4 * 4);
        rb[i] = *(const float4*)(W + (size_t)(k0 + lrow + i * 32) * Hn + n0 + lc4 * 4);
    }

    for (int kt = 0; kt < 4; ++kt) {
        __syncthreads();                // prev compute done before overwrite
        #pragma unroll
        for (int i = 0; i < 2; ++i) {   // regs -> LDS (waits vmcnt here)
            int row = lrow + i * 32;
            s_a[lc4 * 4 + 0][row] = ra[i].x;
            s_a[lc4 * 4 + 1][row] = ra[i].y;
            s_a[lc4 * 4 + 2][row] = ra[i].z;
            s_a[lc4 * 4 + 3][row] = ra[i].w;
            *(float4*)&s_b[row][lc4 * 4] = rb[i];
        }
        __syncthreads();
        if (kt < 3) {                   // prefetch kt+1 (overlaps compute)
            const int d0n = k0 + (kt + 1) * PBK;
            #pragma unroll
            for (int i = 0; i < 2; ++i) {
                ra[i] = *(const float4*)(Asrc + (size_t)(m0 + lrow + i * 32) * Dn + d0n + lc4 * 4);
                rb[i] = *(const float4*)(W + (size_t)(d0n + lrow + i * 32) * Hn + n0 + lc4 * 4);
            }
        }
        #pragma unroll
        for (int kk = 0; kk < 32; ++kk) {
            float4 a4 = *(const float4*)&s_a[kklo + kk][trow * 4];
            float4 b4 = *(const float4*)&s_b[kklo + kk][tcol * 4];
            float a[4] = {a4.x, a4.y, a4.z, a4.w};
            float b[4] = {b4.x, b4.y, b4.z, b4.w};
            #pragma unroll
            for (int i = 0; i < 4; ++i)
                #pragma unroll
                for (int j = 0; j < 4; ++j)
                    acc[i][j] += a[i] * b[j];
        }
    }

    // merge the two k-halves through LDS (s_a region: 256*17 floats,
    // stride 17 keeps the scalar accesses conflict-free)
    __syncthreads();
    float* red = &s_a[0][0];
    if (kh) {
        #pragma unroll
        for (int i = 0; i < 4; ++i)
            #pragma unroll
            for (int j = 0; j < 4; ++j)
                red[tt * 17 + i * 4 + j] = acc[i][j];
    }
    __syncthreads();
    if (!kh) {
        #pragma unroll
        for (int i = 0; i < 4; ++i) {
            float4 o;
            o.x = acc[i][0] + red[tt * 17 + i * 4 + 0];
            o.y = acc[i][1] + red[tt * 17 + i * 4 + 1];
            o.z = acc[i][2] + red[tt * 17 + i * 4 + 2];
            o.w = acc[i][3] + red[tt * 17 + i * 4 + 3];
            *(float4*)(Dst + (size_t)(trow * 4 + i) * Hn + n0 + tcol * 4) = o;
        }
    }
}

// ---------------------------------------------------------------------------
// Kernel 2: e = exp(score) (max-free: |score| <= sum|wv|) + atomic rowsum.
// v3: stages k-tile and q-tile as the SUM of the two split-K partial buffers
// (extra ~16 KB L2 reads per block; proj needs no atomics/extra memset).
// ---------------------------------------------------------------------------
#define SK_KT 16
#define SK_PAD 260

__global__ __launch_bounds__(256) void score_kernel(
    const float* __restrict__ proj0, const float* __restrict__ proj1,
    const float* __restrict__ wv, const int* __restrict__ valid_lens,
    float* __restrict__ escores, float* __restrict__ rowsum)
{
    const int blk = blockIdx.x;             // ((b*32 + qt)*64 + kt)
    const int kt = blk & 63;
    const int qt = (blk >> 6) & 31;
    const int b  = blk >> 11;
    const int vlen = valid_lens[b];
    const int k0 = kt * SK_KT;
    if (k0 >= vlen) return;                 // fully-masked tile
    const int q0 = qt * 4;
    const int t = threadIdx.x;

    __shared__ float s_k[SK_KT * SK_PAD];   // 16640 B
    __shared__ float s_q[4 * Hn];           // 4 KB
    __shared__ float s_wv[Hn];              // 1 KB

    {
        const float4* k0p = reinterpret_cast<const float4*>(
            proj0 + ((size_t)512 + (size_t)b * Kn + k0) * Hn);
        const float4* k1p = reinterpret_cast<const float4*>(
            proj1 + ((size_t)512 + (size_t)b * Kn + k0) * Hn);
        #pragma unroll
        for (int i = 0; i < 4; ++i) {       // 16 rows x 64 float4
            int idx = t + i * 256;
            int row = idx >> 6, c4 = idx & 63;
            float4 a = k0p[idx];
            float4 c = k1p[idx];
            a.x += c.x; a.y += c.y; a.z += c.z; a.w += c.w;
            *reinterpret_cast<float4*>(&s_k[row * SK_PAD + c4 * 4]) = a;
        }
        float4 qa = reinterpret_cast<const float4*>(
            proj0 + ((size_t)b * Qn + q0) * Hn)[t];
        float4 qb = reinterpret_cast<const float4*>(
            proj1 + ((size_t)b * Qn + q0) * Hn)[t];
        qa.x += qb.x; qa.y += qb.y; qa.z += qb.z; qa.w += qb.w;
        reinterpret_cast<float4*>(s_q)[t] = qa;
        if (t < 64)
            reinterpret_cast<float4*>(s_wv)[t] =
                reinterpret_cast<const float4*>(wv)[t];
    }
    __syncthreads();

    const int wave = t >> 6;
    const int lane = t & 63;
    const int kloc = lane & 15;
    const int hq   = lane >> 4;             // h-quarter: 64 h each

    const float4* kr = reinterpret_cast<const float4*>(&s_k[kloc * SK_PAD + hq * 64]);
    const float4* qr = reinterpret_cast<const float4*>(&s_q[wave * Hn + hq * 64]);
    const float4* wr = reinterpret_cast<const float4*>(&s_wv[hq * 64]);

    float s = 0.0f;
    #pragma unroll
    for (int i = 0; i < 16; ++i) {          // 16 float4 = 64 h per lane
        float4 kv = kr[i];
        float4 qv = qr[i];
        float4 wq = wr[i];
        s += wq.x * fast_tanh(qv.x + kv.x);
        s += wq.y * fast_tanh(qv.y + kv.y);
        s += wq.z * fast_tanh(qv.z + kv.z);
        s += wq.w * fast_tanh(qv.w + kv.w);
    }
    s += __shfl_xor(s, 16, 64);
    s += __shfl_xor(s, 32, 64);

    const int k = k0 + kloc;
    float e = 0.0f;
    if (lane < 16 && k < vlen) {
        e = __expf(s);
        escores[((size_t)b * Qn + q0 + wave) * Kn + k] = e;
    }
    #pragma unroll
    for (int off = 32; off; off >>= 1)
        e += __shfl_xor(e, off, 64);
    if (lane == 0)
        atomicAdd(&rowsum[b * Qn + q0 + wave], e);
}

// ---------------------------------------------------------------------------
// Kernel 3: split-k AV + fused normalization. escores fully zeroed -> masked
// k contribute 0 -> uniform grid, zero imbalance. rowsum is complete before
// this launches (stream order), so each partial is scaled by rcp(rowsum) and
// atomically accumulated straight into the (zeroed) output: reduce_kernel,
// the parts buffer, and 9 MB of intermediate traffic are gone.
// ---------------------------------------------------------------------------
__global__ __launch_bounds__(256) void av_kernel(
    const float* __restrict__ escores, const float* __restrict__ values,
    const float* __restrict__ rowsum, float* __restrict__ out)
{
    const int blk = blockIdx.x;         // (((b*16+qt)*2+dh)*4+kc)
    const int kc = blk & 3;
    const int dh = (blk >> 2) & 1;
    const int qt = (blk >> 3) & 15;
    const int b  = blk >> 7;
    const int t = threadIdx.x;
    const int q0 = qt * 8;
    const int kb = kc * 256;
    const int d  = dh * 256 + t;

    __shared__ float s_e[8][256];       // 8 KB
    #pragma unroll
    for (int i = 0; i < 2; ++i) {
        int idx = t + i * 256;
        int row = idx >> 6, c4 = idx & 63;
        *(float4*)&s_e[row][c4 * 4] = *(const float4*)(
            escores + ((size_t)(b * Qn + q0 + row)) * Kn + kb + c4 * 4);
    }
    __syncthreads();

    const float* vb = values + ((size_t)b * Kn + kb) * Dn + d;
    float acc[8] = {0.f};
    #pragma unroll 2
    for (int k = 0; k < 256; k += 4) {
        float v0 = vb[(size_t)(k + 0) * Dn];
        float v1 = vb[(size_t)(k + 1) * Dn];
        float v2 = vb[(size_t)(k + 2) * Dn];
        float v3 = vb[(size_t)(k + 3) * Dn];
        #pragma unroll
        for (int j = 0; j < 8; ++j) {
            float4 e4 = *(const float4*)&s_e[j][k];  // wave-uniform broadcast
            acc[j] += e4.x * v0 + e4.y * v1 + e4.z * v2 + e4.w * v3;
        }
    }
    float* op = out + ((size_t)(b * Qn + q0)) * Dn + d;
    #pragma unroll
    for (int j = 0; j < 8; ++j) {
        float inv = __builtin_amdgcn_rcpf(rowsum[b * Qn + q0 + j]);
        atomicAdd(op + (size_t)j * Dn, acc[j] * inv);
    }
}

// ---------------------------------------------------------------------------
extern "C" void kernel_launch(void* const* d_in, const int* in_sizes, int n_in,
                              void* d_out, int out_size, void* d_ws, size_t ws_size,
                              hipStream_t stream) {
    const float* queries    = (const float*)d_in[0];
    const float* keys       = (const float*)d_in[1];
    const float* values     = (const float*)d_in[2];
    const int*   valid_lens = (const int*)  d_in[3];
    const float* Wq         = (const float*)d_in[4];
    const float* Wk         = (const float*)d_in[5];
    const float* wv         = (const float*)d_in[6];
    float* out = (float*)d_out;

    // proj partial layout: rows 0..511 = qproj (B*Q), rows 512..4607 = kproj
    const size_t PROJ_F = (size_t)4608 * Hn;      // 1179648 floats each
    float* proj0   = (float*)d_ws;
    float* proj1   = proj0 + PROJ_F;
    float* escores = proj1 + PROJ_F;              // [B*Q, K]  524288 f
    float* rowsum  = escores + (size_t)Bn * Qn * Kn;  // [B*Q]  512 f

    // zero escores (masked k stay 0) + rowsum in one memset; zero out for
    // the fused atomic AV accumulation
    hipMemsetAsync(escores, 0, (size_t)(Bn * Qn * Kn + Bn * Qn) * sizeof(float),
                   stream);
    hipMemsetAsync(out, 0, (size_t)Bn * Qn * Dn * sizeof(float), stream);
    proj_kernel<<<576, 512, 0, stream>>>(queries, keys, Wq, Wk, valid_lens,
                                         proj0, proj1);
    score_kernel<<<Bn * 32 * 64, 256, 0, stream>>>(proj0, proj1, wv,
                                                   valid_lens, escores, rowsum);
    av_kernel<<<512, 256, 0, stream>>>(escores, values, rowsum, out);
}